// Round 10
// baseline (269.317 us; speedup 1.0000x reference)
//
#include <hip/hip_runtime.h>
#include <hip/hip_bf16.h>

// Problem constants
#define NOUT  4096
#define KDIM  1024   // N_SPARSE
#define MROWS 8192   // BATCH*SEQ

typedef __attribute__((ext_vector_type(8))) short bf16x8;    // 8 bf16 = 4 VGPRs
typedef __attribute__((ext_vector_type(16))) float f32x16;   // MFMA 32x32 accumulator

__device__ __forceinline__ unsigned short f2bf(float f) {
  union { float f; unsigned int u; } c; c.f = f;
  unsigned int lsb = (c.u >> 16) & 1u;
  c.u += 0x7fffu + lsb;
  return (unsigned short)(c.u >> 16);
}

__device__ __forceinline__ void gload_lds16(const void* g, void* l) {
  __builtin_amdgcn_global_load_lds(
      (const __attribute__((address_space(1))) void*)g,
      (__attribute__((address_space(3))) void*)l, 16, 0, 0);
}

#define FENCE() asm volatile("" ::: "memory")
#define BAR() do { FENCE(); __builtin_amdgcn_s_barrier(); FENCE(); } while (0)
#define VMW(n) asm volatile("s_waitcnt vmcnt(" #n ")" ::: "memory")

// ---------------------------------------------------------------------------
// Pass 1 (measured-best variant, ~33 us): blocks [0,2048) gather+convert
// 4 x-rows each via LDS row staging; blocks [2048,2560) convert W.
// ---------------------------------------------------------------------------
__global__ __launch_bounds__(512) void prep(const float* __restrict__ x,
                                            const void* __restrict__ idx_raw,
                                            const float* __restrict__ w,
                                            unsigned short* __restrict__ xg,
                                            unsigned short* __restrict__ wb) {
  __shared__ float rows[16384];   // 64 KiB: 4 rows of 4096 f32
  __shared__ int sidx[1024];
  const int b = blockIdx.x;
  const int t = threadIdx.x;

  if (b < 2048) {
    const long long* p64 = (const long long*)idx_raw;
    const int* p32 = (const int*)idx_raw;
    // int64 vs int32 detection: for int32 data, element0-as-int64 >= 2^32
    // (sorted unique indices, second word >= 1), so `< 4096` discriminates.
    const bool is64 = ((unsigned long long)p64[0]) < 4096ull;
    const float* src = x + (size_t)b * 4 * 4096;
#pragma unroll
    for (int i = 0; i < 8; ++i)
      ((float4*)rows)[t + 512 * i] = ((const float4*)src)[t + 512 * i];
    if (is64) {
      sidx[t] = (int)p64[t];
      sidx[t + 512] = (int)p64[t + 512];
    } else {
      sidx[t] = p32[t];
      sidx[t + 512] = p32[t + 512];
    }
    __syncthreads();
    ushort4* dst = (ushort4*)(xg + (size_t)b * 4 * 1024);
#pragma unroll
    for (int i = 0; i < 2; ++i) {
      const int q = t + 512 * i;      // ushort4 index within 4 output rows
      const int e = 4 * q;
      const int rbase = (e >> 10) * 4096;
      const int k = e & 1023;
      ushort4 o;
      o.x = f2bf(rows[rbase + sidx[k + 0]]);
      o.y = f2bf(rows[rbase + sidx[k + 1]]);
      o.z = f2bf(rows[rbase + sidx[k + 2]]);
      o.w = f2bf(rows[rbase + sidx[k + 3]]);
      dst[q] = o;
    }
  } else {
    const int i0 = (b - 2048) * 2048 + t;
#pragma unroll
    for (int j = 0; j < 4; ++j) {
      float4 v = ((const float4*)w)[i0 + 512 * j];
      ushort4 o;
      o.x = f2bf(v.x); o.y = f2bf(v.y); o.z = f2bf(v.z); o.w = f2bf(v.w);
      ((ushort4*)wb)[i0 + 512 * j] = o;
    }
  }
}

// ---------------------------------------------------------------------------
// Pass 2: 256x256 tile, BK=64, **1024 threads = 16 waves (4x4 grid,
// 64x64/wave)** -> 4 waves/SIMD inside one block. Same HBM traffic as the
// round-7 256² kernel (FETCH ~74 MB compulsory), same round-5
// proven-conflict-free swizzle, same round-2 proven loop shape:
//   STAGE(next K-tile) -> VMW(4) -> BAR -> 16 ds_read + 16 MFMA -> BAR.
// Mechanism under test: 4 waves/SIMD interleave ds_read bursts with MFMA
// clusters within each phase (round 7 had only 2 waves/SIMD).
// Per-wave: acc[2][2] f32x16 = 64 AGPR; round 9 measured 56 VGPR for this
// per-wave shape -> fits the 128-reg cap that 16 waves/block mandates.
//
// Swizzle: granule(row,c) = c ^ (row&7) ^ ((row>>3)&3); staging = linear
// gload_lds dest + inverse-XOR'd global source; ds_read applies same XOR
// (all row bases are multiples of 32 -> reduces to (l31&7)^(l31>>3)).
// ---------------------------------------------------------------------------
__global__ __launch_bounds__(1024, 4) void gemm1k(const unsigned short* __restrict__ A,
                                                  const unsigned short* __restrict__ B,
                                                  float* __restrict__ C) {
  __shared__ __align__(16) unsigned short lds[65536];  // 128 KiB: 2 bufs x (A 32K | B 32K)

  const int tid = threadIdx.x;
  const int lane = tid & 63;
  const int wid = tid >> 6;                    // 0..15
  const int wm = wid >> 2, wn = wid & 3;       // 4 x 4 wave grid, per-wave 64x64
  const int l31 = lane & 31, lh = lane >> 5;   // 32x32 frag: row, k-half

  const int bn0 = blockIdx.x * 256;
  const int bm0 = blockIdx.y * 256;

  // ---- staging map: thread t owns linear 16B slot t per 128-row round;
  // row pr = t>>3, granule g = t&7 holds global k-octet
  // c = g ^ (pr&7) ^ ((pr>>3)&3).
  const int pr = tid >> 3;                                   // 0..127
  const int cg = (tid & 7) ^ (pr & 7) ^ ((pr >> 3) & 3);
  const unsigned short* Ag = A + (size_t)(bm0 + pr) * KDIM + cg * 8;
  const unsigned short* Bg = B + (size_t)(bn0 + pr) * KDIM + cg * 8;
  const int tid8 = tid * 8;

  // ---- ds_read map: element (row R, octet c) at ushort offset
  // R*64 + (c ^ (R&7) ^ ((R>>3)&3))*8. Frag rows = base32 + l31.
  const int sw8 = (l31 & 7) ^ (l31 >> 3);
  const int cK0 = (lh ^ sw8) * 8;   // kb=0 (octet = 2*kb + lh)
  const int cK1 = cK0 ^ 16;         // kb=1
  const int cK2 = cK0 ^ 32;         // kb=2
  const int cK3 = cK0 ^ 48;         // kb=3
  const int aOff = wm * 4096 + l31 * 64;            // + mf*2048 (+ d*32768)
  const int bOff = 16384 + wn * 4096 + l31 * 64;    // + nf*2048

  f32x16 acc[2][2] = {};

#define STAGE(d, t) do {                                                \
    unsigned short* Lb = lds + (d) * 32768;                             \
    gload_lds16(Ag + (t) * 64,                        Lb + tid8);       \
    gload_lds16(Ag + (size_t)128 * KDIM + (t) * 64,   Lb + 8192 + tid8);  \
    gload_lds16(Bg + (t) * 64,                        Lb + 16384 + tid8); \
    gload_lds16(Bg + (size_t)128 * KDIM + (t) * 64,   Lb + 24576 + tid8); \
  } while (0)

  STAGE(0, 0);

  for (int t = 0; t < 16; ++t) {
    const int d = t & 1;
    if (t < 15) {
      STAGE(d ^ 1, t + 1);   // prefetch next K-tile into other buffer
      VMW(4);                // current tile landed; next tile's 4 in flight
    } else {
      VMW(0);
    }
    BAR();
    const unsigned short* La = lds + d * 32768;
    bf16x8 a0[4], a1[4], b0[4], b1[4];
    a0[0] = *(const bf16x8*)(La + aOff + cK0);
    a0[1] = *(const bf16x8*)(La + aOff + cK1);
    a0[2] = *(const bf16x8*)(La + aOff + cK2);
    a0[3] = *(const bf16x8*)(La + aOff + cK3);
    a1[0] = *(const bf16x8*)(La + aOff + 2048 + cK0);
    a1[1] = *(const bf16x8*)(La + aOff + 2048 + cK1);
    a1[2] = *(const bf16x8*)(La + aOff + 2048 + cK2);
    a1[3] = *(const bf16x8*)(La + aOff + 2048 + cK3);
    b0[0] = *(const bf16x8*)(La + bOff + cK0);
    b0[1] = *(const bf16x8*)(La + bOff + cK1);
    b0[2] = *(const bf16x8*)(La + bOff + cK2);
    b0[3] = *(const bf16x8*)(La + bOff + cK3);
    b1[0] = *(const bf16x8*)(La + bOff + 2048 + cK0);
    b1[1] = *(const bf16x8*)(La + bOff + 2048 + cK1);
    b1[2] = *(const bf16x8*)(La + bOff + 2048 + cK2);
    b1[3] = *(const bf16x8*)(La + bOff + 2048 + cK3);
    __builtin_amdgcn_s_setprio(1);
#pragma unroll
    for (int kb = 0; kb < 4; ++kb) {
      acc[0][0] = __builtin_amdgcn_mfma_f32_32x32x16_bf16(a0[kb], b0[kb], acc[0][0], 0, 0, 0);
      acc[0][1] = __builtin_amdgcn_mfma_f32_32x32x16_bf16(a0[kb], b1[kb], acc[0][1], 0, 0, 0);
      acc[1][0] = __builtin_amdgcn_mfma_f32_32x32x16_bf16(a1[kb], b0[kb], acc[1][0], 0, 0, 0);
      acc[1][1] = __builtin_amdgcn_mfma_f32_32x32x16_bf16(a1[kb], b1[kb], acc[1][1], 0, 0, 0);
    }
    __builtin_amdgcn_s_setprio(0);
    BAR();   // protect this buffer from next iteration's prefetch overwrite
  }
#undef STAGE

  // Epilogue. 32x32 C/D (m74/m101): col = lane&31,
  // row = (reg&3) + 8*(reg>>2) + 4*(lane>>5).
  float* base = C + (size_t)(bm0 + wm * 64) * NOUT + bn0 + wn * 64;
#pragma unroll
  for (int mf = 0; mf < 2; ++mf)
#pragma unroll
    for (int nf = 0; nf < 2; ++nf) {
      f32x16 v = acc[mf][nf];
#pragma unroll
      for (int r = 0; r < 16; ++r) {
        const int rowi = mf * 32 + (r & 3) + 8 * (r >> 2) + 4 * lh;
        base[(size_t)rowi * NOUT + nf * 32 + l31] = v[r];
      }
    }
}

extern "C" void kernel_launch(void* const* d_in, const int* in_sizes, int n_in,
                              void* d_out, int out_size, void* d_ws, size_t ws_size,
                              hipStream_t stream) {
  const float* x   = (const float*)d_in[0];   // [4,2048,4096] f32
  const float* sv  = (const float*)d_in[1];   // [4096,1024] f32
  const void*  idx = d_in[2];                 // [1024] int32 or int64
  float* out = (float*)d_out;                 // [4,2048,4096] f32

  unsigned short* xg = (unsigned short*)d_ws;                 // [8192,1024] bf16
  unsigned short* wb = xg + (size_t)MROWS * KDIM;             // [4096,1024] bf16

  prep<<<2560, 512, 0, stream>>>(x, idx, sv, xg, wb);

  dim3 grid(NOUT / 256, MROWS / 256);  // (16, 32) = 512 blocks
  gemm1k<<<grid, 1024, 0, stream>>>(xg, wb, out);
}